// Round 1
// baseline (1442.596 us; speedup 1.0000x reference)
//
#include <hip/hip_runtime.h>

#define CAM_SCALE (256.0f / 1920.0f)
#define NPTS 30000
#define NBATCH 8
#define OUTC 963

// ---------------- NCHW -> NHWC tiled transpose ----------------
// src: [B, C, HW] (B via blockIdx.z), dst: [B, HW, C]
// block (32,8); grid (HW/32, C/32, B). C and HW are multiples of 32.
__global__ __launch_bounds__(256) void transpose_chw_hwc(
    const float* __restrict__ src, float* __restrict__ dst, int C, int HW) {
  __shared__ float tile[32][33];  // +1 pad: conflict-free both directions
  const size_t plane = (size_t)C * HW;
  src += (size_t)blockIdx.z * plane;
  dst += (size_t)blockIdx.z * plane;
  const int p0 = blockIdx.x * 32;
  const int c0 = blockIdx.y * 32;
  const int tx = threadIdx.x, ty = threadIdx.y;
#pragma unroll
  for (int i = 0; i < 4; ++i) {
    const int c = c0 + ty + i * 8;
    tile[ty + i * 8][tx] = src[(size_t)c * HW + (p0 + tx)];
  }
  __syncthreads();
#pragma unroll
  for (int i = 0; i < 4; ++i) {
    const int p = p0 + ty + i * 8;
    dst[(size_t)p * C + (c0 + tx)] = tile[tx][ty + i * 8];
  }
}

// ---------------- projection + 4-level bilinear gather ----------------
// One block (256 threads) per point. blockIdx & 7 = batch (XCD L2 affinity).
__global__ __launch_bounds__(256) void gproj_sample(
    const float* __restrict__ inputs, const float* __restrict__ camK,
    const float* __restrict__ resolution,
    const float* __restrict__ f0, const float* __restrict__ f1,
    const float* __restrict__ f2, const float* __restrict__ f3,
    float* __restrict__ out, int nhwc) {
  const int blk = blockIdx.x;
  const int b = blk & 7;
  const int n = blk >> 3;
  const size_t pt = (size_t)b * NPTS + n;

  const float X = inputs[pt * 3 + 0];
  const float Y = inputs[pt * 3 + 1];
  const float Z = inputs[pt * 3 + 2];

  const float half0 = (resolution[0] - 1.0f) * 0.5f;
  const float half1 = (resolution[1] - 1.0f) * 0.5f;

  const float K00 = camK[b * 9 + 0] * CAM_SCALE;
  const float K01 = camK[b * 9 + 1] * CAM_SCALE;
  const float K02 = camK[b * 9 + 2] * CAM_SCALE;
  const float K11 = camK[b * 9 + 4] * CAM_SCALE;
  const float K12 = camK[b * 9 + 5] * CAM_SCALE;

  const float Zp = Z - 0.8f;  // MESH_POS = (0,0,-0.8)
  const float w = (-K00 * X - K01 * Y) / Zp + K02 - half0;
  const float h = K11 * (Y / Zp) + K12 - half1;
  const float gx = fminf(fmaxf(w / half0, -1.0f), 1.0f);
  const float gy = fminf(fmaxf(h / half1, -1.0f), 1.0f);

  const size_t orow = pt * (size_t)OUTC;

  for (int oc = threadIdx.x; oc < OUTC; oc += 256) {
    float v;
    if (oc < 3) {
      v = (oc == 0) ? X : (oc == 1 ? Y : Z);
    } else {
      const int t = oc - 3;
      const float* f;
      int c, C, H, W;
      if (t < 64)       { f = f0; C = 64;  H = 128; W = 128; c = t; }
      else if (t < 192) { f = f1; C = 128; H = 64;  W = 64;  c = t - 64; }
      else if (t < 448) { f = f2; C = 256; H = 32;  W = 32;  c = t - 192; }
      else              { f = f3; C = 512; H = 16;  W = 16;  c = t - 448; }

      const float x = ((gx + 1.0f) * W - 1.0f) * 0.5f;
      const float y = ((gy + 1.0f) * H - 1.0f) * 0.5f;
      const float x0f = floorf(x), y0f = floorf(y);
      const int x0 = (int)x0f, y0 = (int)y0f;
      const int x1 = x0 + 1, y1 = y0 + 1;
      const float wx1 = x - x0f, wx0 = 1.0f - wx1;
      const float wy1 = y - y0f, wy0 = 1.0f - wy1;
      const bool vx0 = (x0 >= 0) && (x0 < W);
      const bool vx1 = (x1 >= 0) && (x1 < W);
      const bool vy0 = (y0 >= 0) && (y0 < H);
      const bool vy1 = (y1 >= 0) && (y1 < H);
      const int HW = H * W;

      v = 0.0f;
      if (nhwc) {
        const size_t basep = (size_t)b * HW;
        if (vy0) {
          const size_t r = (basep + (size_t)y0 * W) * C + c;
          if (vx0) v += wx0 * wy0 * f[r + (size_t)x0 * C];
          if (vx1) v += wx1 * wy0 * f[r + (size_t)x1 * C];
        }
        if (vy1) {
          const size_t r = (basep + (size_t)y1 * W) * C + c;
          if (vx0) v += wx0 * wy1 * f[r + (size_t)x0 * C];
          if (vx1) v += wx1 * wy1 * f[r + (size_t)x1 * C];
        }
      } else {
        const size_t basec = ((size_t)b * C + c) * (size_t)HW;
        if (vy0) {
          if (vx0) v += wx0 * wy0 * f[basec + y0 * W + x0];
          if (vx1) v += wx1 * wy0 * f[basec + y0 * W + x1];
        }
        if (vy1) {
          if (vx0) v += wx0 * wy1 * f[basec + y1 * W + x0];
          if (vx1) v += wx1 * wy1 * f[basec + y1 * W + x1];
        }
      }
    }
    out[orow + oc] = v;
  }
}

extern "C" void kernel_launch(void* const* d_in, const int* in_sizes, int n_in,
                              void* d_out, int out_size, void* d_ws, size_t ws_size,
                              hipStream_t stream) {
  const float* resolution = (const float*)d_in[0];
  const float* feat0 = (const float*)d_in[1];  // [8,64,128,128]
  const float* feat1 = (const float*)d_in[2];  // [8,128,64,64]
  const float* feat2 = (const float*)d_in[3];  // [8,256,32,32]
  const float* feat3 = (const float*)d_in[4];  // [8,512,16,16]
  const float* inputs = (const float*)d_in[5]; // [8,30000,3]
  const float* camK = (const float*)d_in[6];   // [8,3,3]
  float* out = (float*)d_out;

  const size_t n0 = (size_t)NBATCH * 64 * 128 * 128;
  const size_t n1 = (size_t)NBATCH * 128 * 64 * 64;
  const size_t n2 = (size_t)NBATCH * 256 * 32 * 32;
  const size_t n3 = (size_t)NBATCH * 512 * 16 * 16;
  const size_t need = (n0 + n1 + n2 + n3) * sizeof(float);

  const dim3 tb(32, 8, 1);
  if (ws_size >= need) {
    float* ft0 = (float*)d_ws;
    float* ft1 = ft0 + n0;
    float* ft2 = ft1 + n1;
    float* ft3 = ft2 + n2;
    transpose_chw_hwc<<<dim3(16384 / 32, 64 / 32, NBATCH), tb, 0, stream>>>(feat0, ft0, 64, 16384);
    transpose_chw_hwc<<<dim3(4096 / 32, 128 / 32, NBATCH), tb, 0, stream>>>(feat1, ft1, 128, 4096);
    transpose_chw_hwc<<<dim3(1024 / 32, 256 / 32, NBATCH), tb, 0, stream>>>(feat2, ft2, 256, 1024);
    transpose_chw_hwc<<<dim3(256 / 32, 512 / 32, NBATCH), tb, 0, stream>>>(feat3, ft3, 512, 256);
    gproj_sample<<<NBATCH * NPTS, 256, 0, stream>>>(inputs, camK, resolution,
                                                    ft0, ft1, ft2, ft3, out, 1);
  } else {
    // Fallback: direct NCHW gather (correct, slower).
    gproj_sample<<<NBATCH * NPTS, 256, 0, stream>>>(inputs, camK, resolution,
                                                    feat0, feat1, feat2, feat3, out, 0);
  }
}